// Round 15
// baseline (6810.863 us; speedup 1.0000x reference)
//
#include <hip/hip_runtime.h>

// 2-layer LSTM (B=256,T=512,D=64,H=512) + FC, fp16 MFMA / fp32 accum.
// v14: FOUR independent batch-group chains per block (32 groups x 8 batches).
// Block (pid,jb) serves groups 4pid..4pid+3 with SHARED weight registers.
// Phase p: poll+issue chain p -> GEMM chain p-1 (hides RT) -> tilewr p -> bar.
// Tail: GEMM chain 3 + BATCHED publish (all 4 chains' stores, ONE vmcnt(0)
// drain, 4 flags) + x staging. GB=8 < MFMA M=16: A-row clamped (col&7); the
// duplicate D-rows land in q>=2 lanes which are never staged (D row = 4q+jj).
// Exchange protocol = PROVEN sc1/IF relaxed atomics + vmcnt(0) + monotonic
// hot-line flags + bounded poll (R10/R12/R14 lineage).

typedef _Float16 f16;
typedef _Float16 f16x8 __attribute__((ext_vector_type(8)));
typedef _Float16 f16x4 __attribute__((ext_vector_type(4)));
typedef float    f32x4 __attribute__((ext_vector_type(4)));
typedef unsigned long long u64;

#define T_STEPS 512
#define NBATCH  256
#define DIN     64
#define NHID    512
#define GB      8           // batches per group
#define CBLK    32          // blocks (hid slices) per group
#define NGRP4   32          // number of groups
#define NROWS   64          // gate rows per block: 4 gates x 16 hidden
#define HS      (NHID + 8)  // padded tile row stride (f16)
#define XS      (DIN + 8)
#define FSTRIDE 32          // dwords per flag line (128B)

__device__ __forceinline__ f32x4 mfma16(f16x8 a, f16x8 b, f32x4 c) {
    return __builtin_amdgcn_mfma_f32_16x16x32_f16(a, b, c, 0, 0, 0);
}

__device__ __forceinline__ f16x8 cvt8(const float* p) {
    const float4 v0 = *reinterpret_cast<const float4*>(p);
    const float4 v1 = *reinterpret_cast<const float4*>(p + 4);
    f16x8 r;
    r[0] = (f16)v0.x; r[1] = (f16)v0.y; r[2] = (f16)v0.z; r[3] = (f16)v0.w;
    r[4] = (f16)v1.x; r[5] = (f16)v1.y; r[6] = (f16)v1.z; r[7] = (f16)v1.w;
    return r;
}

__device__ __forceinline__ void act4(const f32x4 gv, const int gate,
                                     float* cc, float* hh)
{
#pragma unroll
    for (int jj = 0; jj < 4; ++jj) {
        const float v  = gv[jj];
        const float xs = (gate == 2) ? 2.0f * v : v;
        const float ee = exp2f(-1.44269504f * xs);
        const float sg = 1.0f / (1.0f + ee);
        const float a  = (gate == 2) ? (2.0f * sg - 1.0f) : sg;   // g uses tanh
        const float a1 = __shfl_xor(a, 1, 64);
        const float a2 = __shfl_xor(a, 2, 64);
        const float a3 = __shfl_xor(a, 3, 64);
        int d;
        float vi, vf, vg, vo;
        d = gate;     vi = d == 0 ? a : d == 1 ? a1 : d == 2 ? a2 : a3;
        d = gate ^ 1; vf = d == 0 ? a : d == 1 ? a1 : d == 2 ? a2 : a3;
        d = gate ^ 2; vg = d == 0 ? a : d == 1 ? a1 : d == 2 ? a2 : a3;
        d = gate ^ 3; vo = d == 0 ? a : d == 1 ? a1 : d == 2 ? a2 : a3;
        const float cn = vf * cc[jj] + vi * vg;
        cc[jj] = cn;
        const float e2 = exp2f(-2.88539008f * cn);   // tanh(c) = 2/(1+e^-2c)-1
        const float th = 2.0f / (1.0f + e2) - 1.0f;
        hh[jj] = vo * th;
    }
}

__global__ __launch_bounds__(512, 2) void lstm_fused(
    const f16*  __restrict__ xpk,      // [T][B][DIN] fp16 time-major
    const float* __restrict__ wih0, const float* __restrict__ whh0,
    const float* __restrict__ bih0, const float* __restrict__ bhh0,
    const float* __restrict__ wih1, const float* __restrict__ whh1,
    const float* __restrict__ bih1, const float* __restrict__ bhh1,
    f16* __restrict__ hbuf0,           // [2][B][NHID] layer0 h exchange
    f16* __restrict__ hbuf1,           // [2][B][NHID] layer1 h exchange
    float* __restrict__ hlast,         // [B][NHID] f32 final h1
    unsigned* flags0, unsigned* flags1) // [NGRP4*CBLK*FSTRIDE] monotonic, memset 0
{
    __shared__ f16 hT0[4][GB * HS];         // h0(s-1) tiles, chains 0..3
    __shared__ f16 hT1[4][GB * HS];         // h1(s-2) tiles
    __shared__ f16 xTile[4][3][GB * XS];    // x tiles [chain][slot]
    __shared__ f16 hs0[4][GB * 16];         // publish staging per chain
    __shared__ f16 hs1[4][GB * 16];
    __shared__ float Lb0[NROWS], Lb1[NROWS];
    __shared__ unsigned pubcnt[2][2];       // [eng][parity] wave-arrival count

    const int tid = threadIdx.x;
    const int pid = blockIdx.x & 7;
    const int jb  = blockIdx.x >> 3;
    const int bbP = pid * 32;               // batch base of this pod

    if (tid < 4) reinterpret_cast<unsigned*>(pubcnt)[tid] = 0u;
    if (tid < NROWS) {
        const int gr = (tid & 3) * NHID + jb * 16 + (tid >> 2);
        Lb0[tid] = bih0[gr] + bhh0[gr];
        Lb1[tid] = bih1[gr] + bhh1[gr];
    }

    const int w    = tid >> 6;          // wave 0..7
    const int eng  = w >> 2;            // 0: layer0, 1: layer1
    const int wr   = w & 3;
    const int l    = tid & 63;
    const int col  = l & 15;
    const int colc = col & (GB - 1);    // clamped A-row (GB=8)
    const int q    = l >> 4;
    const int q8   = q << 3;
    const int n    = (wr << 4) | col;   // gate row 0..63
    const int gate = n & 3;
    const int hl   = n >> 2;
    const int grow = (n & 3) * NHID + jb * 16 + (n >> 2);
    const int rb8  = (wr << 1) | (l & 1);   // staging row 0..7
    const int rc8  = l >> 1;                // staging chunk 0..31

    // ---- weights -> registers (one-time), f32->f16; SHARED by all chains ----
    f16x8 BWx[16], BWh[16];
    if (eng == 0) {
        const float* sx = wih0 + (size_t)grow * DIN + q8;
#pragma unroll
        for (int s = 0; s < 2; ++s) BWx[s] = cvt8(sx + s * 32);
        const float* sh = whh0 + (size_t)grow * NHID + q8;
#pragma unroll
        for (int s = 0; s < 16; ++s) BWh[s] = cvt8(sh + s * 32);
    } else {
        const float* sx = wih1 + (size_t)grow * NHID + q8;
#pragma unroll
        for (int s = 0; s < 16; ++s) BWx[s] = cvt8(sx + s * 32);
        const float* sh = whh1 + (size_t)grow * NHID + q8;
#pragma unroll
        for (int s = 0; s < 16; ++s) BWh[s] = cvt8(sh + s * 32);
    }
    __syncthreads();
    const float bias_n = (eng == 0) ? Lb0[n] : Lb1[n];

    float cc0[4][4] = {{0,0,0,0},{0,0,0,0},{0,0,0,0},{0,0,0,0}};
    float cc1[4][4] = {{0,0,0,0},{0,0,0,0},{0,0,0,0},{0,0,0,0}};

    // ---- bounded wave-parallel poll of a group's 32 producer counters ----
    auto pollf = [&](const unsigned* flg, int grp, int sp) {
        const unsigned target = (unsigned)(sp + 1);
        const unsigned* fp = flg + (size_t)(grp * CBLK + (l & 31)) * FSTRIDE;
        unsigned spins = 0;
        for (;;) {
            unsigned v = 0xFFFFFFFFu;
            if (l < CBLK)
                v = __hip_atomic_load(fp, __ATOMIC_RELAXED, __HIP_MEMORY_SCOPE_AGENT);
            if (__all(v >= target)) break;
            __builtin_amdgcn_s_sleep(2);
            if (++spins > (1u << 15)) break;   // fail finite, never hang
        }
        asm volatile("" ::: "memory");
    };

    // issue 4x8B sc1 loads of one 8x512 h tile (32B/lane)
    auto ldissue = [&](u64* r, const f16* hb, int par, int bb) {
        const u64* src = reinterpret_cast<const u64*>(
            hb + (size_t)par * (NBATCH * NHID) + (size_t)(bb + rb8) * NHID) + rc8 * 4;
#pragma unroll
        for (int j = 0; j < 4; ++j)
            r[j] = __hip_atomic_load(src + j, __ATOMIC_RELAXED, __HIP_MEMORY_SCOPE_AGENT);
    };
    auto tilewr = [&](f16* t, const u64* r) {
        f16* dst = t + rb8 * HS + rc8 * 16;
#pragma unroll
        for (int j = 0; j < 4; ++j)
            *reinterpret_cast<u64*>(dst + j * 4) = r[j];
    };

    // ---- batched publish: 4 chains' stores -> ONE vmcnt(0) -> 4 flags ----
    auto puball = [&](f16* hb, unsigned* flg, f16 (*hsarr)[GB * 16], int sp, int eci) {
        asm volatile("s_waitcnt lgkmcnt(0)" ::: "memory");  // hstage visible
        if (l < GB) {
#pragma unroll
            for (int c = 0; c < 4; ++c) {
                const u64 v8 = *reinterpret_cast<const u64*>(&hsarr[c][l * 16 + wr * 4]);
                u64* dst = reinterpret_cast<u64*>(
                    hb + (size_t)(sp & 1) * (NBATCH * NHID)
                       + (size_t)(bbP + c * GB + l) * NHID + jb * 16 + wr * 4);
                __hip_atomic_store(dst, v8, __ATOMIC_RELAXED, __HIP_MEMORY_SCOPE_AGENT);
            }
        }
        asm volatile("s_waitcnt vmcnt(0)" ::: "memory");    // one drain for all
        if (l == 0) {
            const unsigned old = atomicAdd(&pubcnt[eci][sp & 1], 1u);
            if (old == 3u) {
                pubcnt[eci][sp & 1] = 0u;
#pragma unroll
                for (int c = 0; c < 4; ++c)
                    __hip_atomic_store(
                        flg + (size_t)((pid * 4 + c) * CBLK + jb) * FSTRIDE,
                        (unsigned)(sp + 1),
                        __ATOMIC_RELAXED, __HIP_MEMORY_SCOPE_AGENT);
            }
        }
    };

    // ---- x staging: wave wr handles chain wr (eng0 only) ----
    auto xstage = [&](int tt) {
        const int row = l & 7;
        const int cb  = l >> 3;   // 0..7
#pragma unroll
        for (int j = 0; j < 2; ++j) {
            const u64 v = *reinterpret_cast<const u64*>(
                xpk + ((size_t)tt * NBATCH + bbP + wr * GB + row) * DIN + (cb * 2 + j) * 4);
            *reinterpret_cast<u64*>(&xTile[wr][tt % 3][row * XS + (cb * 2 + j) * 4]) = v;
        }
    };

    // ---- eng0 chain step: K=64 x-GEMM + K=512 h-GEMM, act, stage ----
    auto comp0 = [&](int c, int s_) {
        const f16* xp = &xTile[c][s_ % 3][0];
        f32x4 e0 = {bias_n, bias_n, bias_n, bias_n};
        f32x4 o0 = {0, 0, 0, 0};
#pragma unroll
        for (int k = 0; k < 2; ++k) {
            const f16x8 a0 = *reinterpret_cast<const f16x8*>(xp + colc * XS + (q + 4*k) * 8);
            if (k & 1) o0 = mfma16(a0, BWx[k], o0); else e0 = mfma16(a0, BWx[k], e0);
        }
        if (s_ >= 1) {
            const f16* t0 = &hT0[c][0];
#pragma unroll
            for (int k = 0; k < 16; ++k) {
                const f16x8 a0 = *reinterpret_cast<const f16x8*>(t0 + colc * HS + (q + 4*k) * 8);
                if (k & 1) o0 = mfma16(a0, BWh[k], o0); else e0 = mfma16(a0, BWh[k], e0);
            }
        }
        const f32x4 gv = e0 + o0;
        float hv[4];
        act4(gv, gate, cc0[c], hv);
        if (gate == 0 && q < 2) {
#pragma unroll
            for (int jj = 0; jj < 4; ++jj)
                hs0[c][(q * 4 + jj) * 16 + hl] = (f16)hv[jj];
        }
    };

    // ---- eng1 chain step: K=512 x-GEMM (h0) + K=512 h-GEMM (h1) ----
    auto comp1 = [&](int c, int sp) {
        f32x4 e0 = {bias_n, bias_n, bias_n, bias_n};
        f32x4 o0 = {0, 0, 0, 0};
        const f16* t0 = &hT0[c][0];
#pragma unroll
        for (int k = 0; k < 16; ++k) {
            const f16x8 a0 = *reinterpret_cast<const f16x8*>(t0 + colc * HS + (q + 4*k) * 8);
            if (k & 1) o0 = mfma16(a0, BWx[k], o0); else e0 = mfma16(a0, BWx[k], e0);
        }
        if (sp >= 1) {
            const f16* t1 = &hT1[c][0];
#pragma unroll
            for (int k = 0; k < 16; ++k) {
                const f16x8 a0 = *reinterpret_cast<const f16x8*>(t1 + colc * HS + (q + 4*k) * 8);
                if (k & 1) o0 = mfma16(a0, BWh[k], o0); else e0 = mfma16(a0, BWh[k], e0);
            }
        }
        const f32x4 gv = e0 + o0;
        float hv[4];
        act4(gv, gate, cc1[c], hv);
        if (sp == T_STEPS - 1) {
            if (gate == 0 && q < 2) {
#pragma unroll
                for (int jj = 0; jj < 4; ++jj)
                    hlast[(size_t)(bbP + c * GB + q * 4 + jj) * NHID + jb * 16 + hl] = hv[jj];
            }
        } else if (gate == 0 && q < 2) {
#pragma unroll
            for (int jj = 0; jj < 4; ++jj)
                hs1[c][(q * 4 + jj) * 16 + hl] = (f16)hv[jj];
        }
    };

    // ---- prologue: stage x slots 0,1 for all 4 chains ----
    if (eng == 0) { xstage(0); xstage(1); }
    __syncthreads();

    u64 r4[4];
    for (int s = 0; s <= T_STEPS; ++s) {
        const bool doh0 = (s >= 1);
        const bool doh1 = (s >= 2);
#pragma unroll
        for (int p = 0; p < 4; ++p) {
            const int grp = pid * 4 + p;
            const int bb  = grp * GB;
            if (eng == 0) {
                if (doh0) { pollf(flags0, grp, s - 1); ldissue(r4, hbuf0, (s - 1) & 1, bb); }
                if (p == 0 && s + 2 < T_STEPS) xstage(s + 2);  // overlaps p0 RT
                if (p >= 1 && s < T_STEPS) comp0(p - 1, s);    // hides chain-p RT
                if (doh0) tilewr(&hT0[p][0], r4);
            } else {
                if (doh1) { pollf(flags1, grp, s - 2); ldissue(r4, hbuf1, (s - 2) & 1, bb); }
                if (p >= 1 && s >= 1) comp1(p - 1, s - 1);
                if (doh1) tilewr(&hT1[p][0], r4);
            }
            __syncthreads();
        }
        // ---- tail: chain 3 compute + batched publish + flags ----
        if (eng == 0) {
            if (s < T_STEPS) {
                comp0(3, s);
                puball(hbuf0, flags0, hs0, s, 0);
            }
        } else {
            if (s >= 1) {
                comp1(3, s - 1);
                if (s < T_STEPS) puball(hbuf1, flags1, hs1, s - 1, 1);
            }
        }
        __syncthreads();
    }
}

// x [B][T][DIN] f32 -> xp [T][B][DIN] f16 (write-coalesced transpose)
__global__ void pack_x(const float* __restrict__ xin, f16* __restrict__ xp) {
    const int i = blockIdx.x * 256 + threadIdx.x;
    const long long e = (long long)i * 4;
    const int d = (int)(e & (DIN - 1));
    const int b = (int)((e >> 6) & (NBATCH - 1));
    const int t = (int)(e >> 14);
    if (t < T_STEPS) {
        const float4 v = *reinterpret_cast<const float4*>(
            xin + ((size_t)b * T_STEPS + t) * DIN + d);
        f16x4 o;
        o[0] = (f16)v.x; o[1] = (f16)v.y; o[2] = (f16)v.z; o[3] = (f16)v.w;
        *reinterpret_cast<f16x4*>(xp + ((size_t)t * NBATCH + b) * DIN + d) = o;
    }
}

__global__ void fc_kernel(const float* __restrict__ hlast, const float* __restrict__ wfc,
                          const float* __restrict__ bfc, float* __restrict__ out) {
    const int wv = threadIdx.x >> 6, l = threadIdx.x & 63;
    const int b  = blockIdx.x * 4 + wv;
    const float* hr = hlast + b * NHID;
    float s = 0.f;
#pragma unroll
    for (int j = 0; j < 8; ++j) s += hr[l + 64 * j] * wfc[l + 64 * j];
#pragma unroll
    for (int off = 32; off; off >>= 1) s += __shfl_xor(s, off, 64);
    if (l == 0) out[b] = s + bfc[0];
}

extern "C" void kernel_launch(void* const* d_in, const int* in_sizes, int n_in,
                              void* d_out, int out_size, void* d_ws, size_t ws_size,
                              hipStream_t stream) {
    const float* x    = (const float*)d_in[0];
    const float* wih0 = (const float*)d_in[1];
    const float* whh0 = (const float*)d_in[2];
    const float* bih0 = (const float*)d_in[3];
    const float* bhh0 = (const float*)d_in[4];
    const float* wih1 = (const float*)d_in[5];
    const float* whh1 = (const float*)d_in[6];
    const float* bih1 = (const float*)d_in[7];
    const float* bhh1 = (const float*)d_in[8];
    const float* wfc  = (const float*)d_in[9];
    const float* bfc  = (const float*)d_in[10];
    float* out = (float*)d_out;

    char* ws = (char*)d_ws;
    const size_t XPK_ELEMS  = (size_t)NBATCH * T_STEPS * DIN;
    const size_t FLAG_ELEMS = (size_t)NGRP4 * CBLK * FSTRIDE;   // 32768 dwords
    size_t off = 0;
    f16* xpk = (f16*)(ws + off);        off += XPK_ELEMS * 2;
    f16* hb0 = (f16*)(ws + off);        off += (size_t)2 * NBATCH * NHID * 2;
    f16* hb1 = (f16*)(ws + off);        off += (size_t)2 * NBATCH * NHID * 2;
    float* hlast = (float*)(ws + off);  off += (size_t)NBATCH * NHID * 4;
    unsigned* flg0 = (unsigned*)(ws + off); off += FLAG_ELEMS * 4;
    unsigned* flg1 = (unsigned*)(ws + off); off += FLAG_ELEMS * 4;

    // flag counters must be zero every call (graph replays!)
    hipMemsetAsync(flg0, 0, 2 * FLAG_ELEMS * 4, stream);

    pack_x<<<(int)(XPK_ELEMS / 4 / 256), 256, 0, stream>>>(x, xpk);

    {
        const f16* in0 = xpk;
        void* a[] = { (void*)&in0,
                      (void*)&wih0, (void*)&whh0, (void*)&bih0, (void*)&bhh0,
                      (void*)&wih1, (void*)&whh1, (void*)&bih1, (void*)&bhh1,
                      (void*)&hb0, (void*)&hb1, (void*)&hlast,
                      (void*)&flg0, (void*)&flg1 };
        hipLaunchCooperativeKernel(lstm_fused, dim3(256), dim3(512), a, 0, stream);
    }

    fc_kernel<<<64, 256, 0, stream>>>(hlast, wfc, bfc, out);
}

// Round 17
// 6146.189 us; speedup vs baseline: 1.1081x; 1.1081x over previous
//
#include <hip/hip_runtime.h>

// 2-layer LSTM (B=256,T=512,D=64,H=512) + FC, fp16 MFMA / fp32 accum.
// v17 = v13b (two chains/block, PROVEN 4.90ms) + PRELOADED handoffs:
// at end of phase2 (right after compB+publish) a single combined 64-lane poll
// (lanes 0-31: group A producer lines, 32-63: group B) + both chains' tile
// loads issued into persistent registers; they fly across B2. Phase0 becomes
// just tilewrA, phase1 just compA+tilewrB -> ~2 fewer exposed RTs/iteration.
// Exchange topology unchanged (all traffic intra-group, blockIdx=const mod 8
// -> XCD-local, the configuration every PASS used; R16 showed cross-XCD sc1
// is unsafe). Protocol = sc1/IF relaxed atomics + per-wave vmcnt(0) + counter
// + monotonic hot-line flags + bounded poll (R10/R12/R14 lineage).

typedef _Float16 f16;
typedef _Float16 f16x8 __attribute__((ext_vector_type(8)));
typedef _Float16 f16x4 __attribute__((ext_vector_type(4)));
typedef float    f32x4 __attribute__((ext_vector_type(4)));
typedef unsigned long long u64;

#define T_STEPS 512
#define NBATCH  256
#define DIN     64
#define NHID    512
#define GB      16          // batches per group
#define CBLK    32          // blocks (hid slices) per group
#define NGRP2   16          // number of groups
#define NROWS   64          // gate rows per block: 4 gates x 16 hidden
#define HS      (NHID + 8)  // padded tile row stride (f16)
#define XS      (DIN + 8)
#define FSTRIDE 32          // dwords per flag line (128B)

__device__ __forceinline__ f32x4 mfma16(f16x8 a, f16x8 b, f32x4 c) {
    return __builtin_amdgcn_mfma_f32_16x16x32_f16(a, b, c, 0, 0, 0);
}

__device__ __forceinline__ f16x8 cvt8(const float* p) {
    const float4 v0 = *reinterpret_cast<const float4*>(p);
    const float4 v1 = *reinterpret_cast<const float4*>(p + 4);
    f16x8 r;
    r[0] = (f16)v0.x; r[1] = (f16)v0.y; r[2] = (f16)v0.z; r[3] = (f16)v0.w;
    r[4] = (f16)v1.x; r[5] = (f16)v1.y; r[6] = (f16)v1.z; r[7] = (f16)v1.w;
    return r;
}

__device__ __forceinline__ void act4(const f32x4 gv, const int gate,
                                     float* cc, float* hh)
{
#pragma unroll
    for (int jj = 0; jj < 4; ++jj) {
        const float v  = gv[jj];
        const float xs = (gate == 2) ? 2.0f * v : v;
        const float ee = exp2f(-1.44269504f * xs);
        const float sg = 1.0f / (1.0f + ee);
        const float a  = (gate == 2) ? (2.0f * sg - 1.0f) : sg;   // g uses tanh
        const float a1 = __shfl_xor(a, 1, 64);
        const float a2 = __shfl_xor(a, 2, 64);
        const float a3 = __shfl_xor(a, 3, 64);
        int d;
        float vi, vf, vg, vo;
        d = gate;     vi = d == 0 ? a : d == 1 ? a1 : d == 2 ? a2 : a3;
        d = gate ^ 1; vf = d == 0 ? a : d == 1 ? a1 : d == 2 ? a2 : a3;
        d = gate ^ 2; vg = d == 0 ? a : d == 1 ? a1 : d == 2 ? a2 : a3;
        d = gate ^ 3; vo = d == 0 ? a : d == 1 ? a1 : d == 2 ? a2 : a3;
        const float cn = vf * cc[jj] + vi * vg;
        cc[jj] = cn;
        const float e2 = exp2f(-2.88539008f * cn);   // tanh(c) = 2/(1+e^-2c)-1
        const float th = 2.0f / (1.0f + e2) - 1.0f;
        hh[jj] = vo * th;
    }
}

__global__ __launch_bounds__(512, 2) void lstm_fused(
    const f16*  __restrict__ xpk,      // [T][B][DIN] fp16 time-major
    const float* __restrict__ wih0, const float* __restrict__ whh0,
    const float* __restrict__ bih0, const float* __restrict__ bhh0,
    const float* __restrict__ wih1, const float* __restrict__ whh1,
    const float* __restrict__ bih1, const float* __restrict__ bhh1,
    f16* __restrict__ hbuf0,           // [2][B][NHID] layer0 h exchange
    f16* __restrict__ hbuf1,           // [2][B][NHID] layer1 h exchange
    float* __restrict__ hlast,         // [B][NHID] f32 final h1
    unsigned* flags0, unsigned* flags1) // [NGRP2*CBLK*FSTRIDE] monotonic, memset 0
{
    __shared__ f16 hT0A[GB * HS], hT0B[GB * HS];   // h0 tiles, chains A/B
    __shared__ f16 hT1A[GB * HS], hT1B[GB * HS];   // h1 tiles
    __shared__ f16 xTile[2][3][GB * XS];           // x tiles [chain][slot]
    __shared__ f16 hs0[2][2][GB * 16];             // publish stage [chain][par]
    __shared__ f16 hs1[2][2][GB * 16];
    __shared__ float Lb0[NROWS], Lb1[NROWS];
    __shared__ unsigned pubcnt[2][2][2];           // [eng][chain][par]

    const int tid = threadIdx.x;
    const int pid = blockIdx.x & 7;
    const int jb  = blockIdx.x >> 3;
    const int gA  = pid * 2, gB_ = pid * 2 + 1;
    const int bbA = gA * GB, bbB = gB_ * GB;

    if (tid < 8) reinterpret_cast<unsigned*>(pubcnt)[tid] = 0u;
    if (tid < NROWS) {
        const int gr = (tid & 3) * NHID + jb * 16 + (tid >> 2);
        Lb0[tid] = bih0[gr] + bhh0[gr];
        Lb1[tid] = bih1[gr] + bhh1[gr];
    }

    const int w    = tid >> 6;          // wave 0..7
    const int eng  = w >> 2;            // 0: layer0, 1: layer1
    const int wr   = w & 3;
    const int l    = tid & 63;
    const int col  = l & 15;
    const int q    = l >> 4;
    const int q8   = q << 3;
    const int n    = (wr << 4) | col;   // gate row 0..63
    const int gate = n & 3;
    const int hl   = n >> 2;
    const int grow = (n & 3) * NHID + jb * 16 + (n >> 2);
    const int rb   = (wr << 2) | (l & 3);   // staging row 0..15
    const int rc   = l >> 2;                // staging chunk 0..15

    // ---- weights -> registers (one-time), f32->f16; SHARED by both chains ----
    f16x8 BWx[16], BWh[16];
    if (eng == 0) {
        const float* sx = wih0 + (size_t)grow * DIN + q8;
#pragma unroll
        for (int s = 0; s < 2; ++s) BWx[s] = cvt8(sx + s * 32);
        const float* sh = whh0 + (size_t)grow * NHID + q8;
#pragma unroll
        for (int s = 0; s < 16; ++s) BWh[s] = cvt8(sh + s * 32);
    } else {
        const float* sx = wih1 + (size_t)grow * NHID + q8;
#pragma unroll
        for (int s = 0; s < 16; ++s) BWx[s] = cvt8(sx + s * 32);
        const float* sh = whh1 + (size_t)grow * NHID + q8;
#pragma unroll
        for (int s = 0; s < 16; ++s) BWh[s] = cvt8(sh + s * 32);
    }
    __syncthreads();
    const float bias_n = (eng == 0) ? Lb0[n] : Lb1[n];

    float cA[4] = {0,0,0,0}, cB[4] = {0,0,0,0};   // cell state per chain

    // ---- combined poll: lanes 0-31 group A lines, 32-63 group B lines ----
    auto poll2 = [&](const unsigned* flg, int sp) {
        const unsigned target = (unsigned)(sp + 1);
        const int grp = (l < 32) ? gA : gB_;
        const unsigned* fp = flg + (size_t)(grp * CBLK + (l & 31)) * FSTRIDE;
        unsigned spins = 0;
        for (;;) {
            const unsigned v = __hip_atomic_load(fp, __ATOMIC_RELAXED,
                                                 __HIP_MEMORY_SCOPE_AGENT);
            if (__all(v >= target)) break;
            __builtin_amdgcn_s_sleep(2);
            if (++spins > (1u << 15)) break;   // fail finite, never hang
        }
        asm volatile("" ::: "memory");
    };

    // issue 8x8B sc1 loads of one 16x512 h tile slice
    auto ldissue = [&](u64* r, const f16* hb, int par, int bb) {
        const u64* src = reinterpret_cast<const u64*>(
            hb + (size_t)par * (NBATCH * NHID) + (size_t)(bb + rb) * NHID) + rc * 8;
#pragma unroll
        for (int j = 0; j < 8; ++j)
            r[j] = __hip_atomic_load(src + j, __ATOMIC_RELAXED, __HIP_MEMORY_SCOPE_AGENT);
    };
    auto tilewr = [&](f16* t, const u64* r) {
        f16* dst = t + rb * HS + rc * 32;
#pragma unroll
        for (int j = 0; j < 8; ++j)
            *reinterpret_cast<u64*>(dst + j * 4) = r[j];
    };

    // in-compute per-wave stripe publish: sc1 stores -> own vmcnt(0) ->
    // LDS counter; 4th wave writes flag = sp+1.
    auto pubwave = [&](f16* hb, unsigned* flg, int grp, int bb, const f16* hsrc,
                       int sp, int eci, int cci) {
        asm volatile("s_waitcnt lgkmcnt(0)" ::: "memory");
        if (l < GB) {
            const u64 v8 = *reinterpret_cast<const u64*>(hsrc + l * 16 + wr * 4);
            u64* dst = reinterpret_cast<u64*>(
                hb + (size_t)(sp & 1) * (NBATCH * NHID)
                   + (size_t)(bb + l) * NHID + jb * 16 + wr * 4);
            __hip_atomic_store(dst, v8, __ATOMIC_RELAXED, __HIP_MEMORY_SCOPE_AGENT);
        }
        asm volatile("s_waitcnt vmcnt(0)" ::: "memory");
        if (l == 0) {
            const unsigned old = atomicAdd(&pubcnt[eci][cci][sp & 1], 1u);
            if (old == 3u) {
                pubcnt[eci][cci][sp & 1] = 0u;
                __hip_atomic_store(flg + (size_t)(grp * CBLK + jb) * FSTRIDE,
                                   (unsigned)(sp + 1),
                                   __ATOMIC_RELAXED, __HIP_MEMORY_SCOPE_AGENT);
            }
        }
    };

    // ---- eng0 step for one chain: K=64 x-GEMM + K=512 h-GEMM, act, publish ----
    auto comp0 = [&](const f16* xp, const f16* t0, float* cc, f16* hst,
                     int grp, int bb, int s_, bool doh, int cci) {
        f32x4 e0 = {bias_n, bias_n, bias_n, bias_n};
        f32x4 o0 = {0,0,0,0};
#pragma unroll
        for (int k = 0; k < 2; ++k) {
            const f16x8 a0 = *reinterpret_cast<const f16x8*>(xp + col * XS + (q + 4*k) * 8);
            if (k & 1) o0 = mfma16(a0, BWx[k], o0); else e0 = mfma16(a0, BWx[k], e0);
        }
        if (doh) {
#pragma unroll
            for (int k = 0; k < 16; ++k) {
                const f16x8 a0 = *reinterpret_cast<const f16x8*>(t0 + col * HS + (q + 4*k) * 8);
                if (k & 1) o0 = mfma16(a0, BWh[k], o0); else e0 = mfma16(a0, BWh[k], e0);
            }
        }
        const f32x4 gv = e0 + o0;
        float hv[4];
        act4(gv, gate, cc, hv);
        if (gate == 0) {
#pragma unroll
            for (int jj = 0; jj < 4; ++jj)
                hst[(q * 4 + jj) * 16 + hl] = (f16)hv[jj];
        }
        pubwave(hbuf0, flags0, grp, bb, hst, s_, 0, cci);
    };

    // ---- eng1 step for one chain: K=512 x-GEMM (h0) + K=512 h-GEMM (h1) ----
    auto comp1 = [&](const f16* t0, const f16* t1, float* cc, f16* hst,
                     int grp, int bb, int sp_, bool doh2, bool last, int cci) {
        f32x4 e0 = {bias_n, bias_n, bias_n, bias_n};
        f32x4 o0 = {0,0,0,0};
#pragma unroll
        for (int k = 0; k < 16; ++k) {
            const f16x8 a0 = *reinterpret_cast<const f16x8*>(t0 + col * HS + (q + 4*k) * 8);
            if (k & 1) o0 = mfma16(a0, BWx[k], o0); else e0 = mfma16(a0, BWx[k], e0);
        }
        if (doh2) {
#pragma unroll
            for (int k = 0; k < 16; ++k) {
                const f16x8 a0 = *reinterpret_cast<const f16x8*>(t1 + col * HS + (q + 4*k) * 8);
                if (k & 1) o0 = mfma16(a0, BWh[k], o0); else e0 = mfma16(a0, BWh[k], e0);
            }
        }
        const f32x4 gv = e0 + o0;
        float hv[4];
        act4(gv, gate, cc, hv);
        if (last) {
            if (gate == 0) {
#pragma unroll
                for (int jj = 0; jj < 4; ++jj)
                    hlast[(size_t)(bb + q * 4 + jj) * NHID + jb * 16 + hl] = hv[jj];
            }
        } else {
            if (gate == 0) {
#pragma unroll
                for (int jj = 0; jj < 4; ++jj)
                    hst[(q * 4 + jj) * 16 + hl] = (f16)hv[jj];
            }
            pubwave(hbuf1, flags1, grp, bb, hst, sp_, 1, cci);
        }
    };

    // ---- x staging for both chains (eng0 only) ----
    auto xstage = [&](int tt) {
        const u64 vA = *reinterpret_cast<const u64*>(
            xpk + ((size_t)tt * NBATCH + bbA + rb) * DIN + rc * 4);
        const u64 vB = *reinterpret_cast<const u64*>(
            xpk + ((size_t)tt * NBATCH + bbB + rb) * DIN + rc * 4);
        *reinterpret_cast<u64*>(xTile[0][tt % 3] + rb * XS + rc * 4) = vA;
        *reinterpret_cast<u64*>(xTile[1][tt % 3] + rb * XS + rc * 4) = vB;
    };

    // ---- prologue: stage xT slots 0,1 for both chains ----
    if (eng == 0) { xstage(0); xstage(1); }
    __syncthreads();

    u64 rA[8], rB[8];   // preloaded tile registers (persist across barriers)
    for (int s = 0; s <= T_STEPS; ++s) {
        // ---- phase0: stage chain-A tile from preloaded registers ----
        if (eng == 0) { if (s >= 1) tilewr(hT0A, rA); }
        else          { if (s >= 2) tilewr(hT1A, rA); }
        __syncthreads();   // B1a: A tiles staged
        // ---- phase1: compute chain A (+publish); stage chain-B tile ----
        if (eng == 0) {
            if (s < T_STEPS)
                comp0(xTile[0][s % 3], hT0A, cA, hs0[0][s & 1], gA, bbA, s, s >= 1, 0);
            if (s >= 1) tilewr(hT0B, rB);
        } else {
            if (s >= 1)
                comp1(hT0A, hT1A, cA, hs1[0][(s - 1) & 1], gA, bbA, s - 1, s >= 2,
                      s == T_STEPS, 0);
            if (s >= 2) tilewr(hT1B, rB);
        }
        __syncthreads();   // B1b: B tiles staged
        // ---- phase2: compute chain B (+publish); preload next-iter tiles ----
        if (eng == 0) {
            if (s < T_STEPS) {
                comp0(xTile[1][s % 3], hT0B, cB, hs0[1][s & 1], gB_, bbB, s, s >= 1, 1);
                // preload h0(s) for iteration s+1 (peers just flagged)
                poll2(flags0, s);
                ldissue(rA, hbuf0, s & 1, bbA);
                ldissue(rB, hbuf0, s & 1, bbB);
            }
            if (s + 2 < T_STEPS) xstage(s + 2);
        } else {
            if (s >= 1) {
                comp1(hT0B, hT1B, cB, hs1[1][(s - 1) & 1], gB_, bbB, s - 1, s >= 2,
                      s == T_STEPS, 1);
                if (s < T_STEPS) {
                    // preload h1(s-1) for iteration s+1
                    poll2(flags1, s - 1);
                    ldissue(rA, hbuf1, (s - 1) & 1, bbA);
                    ldissue(rB, hbuf1, (s - 1) & 1, bbB);
                }
            }
        }
        __syncthreads();   // B2
    }
}

// x [B][T][DIN] f32 -> xp [T][B][DIN] f16 (write-coalesced transpose)
__global__ void pack_x(const float* __restrict__ xin, f16* __restrict__ xp) {
    const int i = blockIdx.x * 256 + threadIdx.x;
    const long long e = (long long)i * 4;
    const int d = (int)(e & (DIN - 1));
    const int b = (int)((e >> 6) & (NBATCH - 1));
    const int t = (int)(e >> 14);
    if (t < T_STEPS) {
        const float4 v = *reinterpret_cast<const float4*>(
            xin + ((size_t)b * T_STEPS + t) * DIN + d);
        f16x4 o;
        o[0] = (f16)v.x; o[1] = (f16)v.y; o[2] = (f16)v.z; o[3] = (f16)v.w;
        *reinterpret_cast<f16x4*>(xp + ((size_t)t * NBATCH + b) * DIN + d) = o;
    }
}

__global__ void fc_kernel(const float* __restrict__ hlast, const float* __restrict__ wfc,
                          const float* __restrict__ bfc, float* __restrict__ out) {
    const int wv = threadIdx.x >> 6, l = threadIdx.x & 63;
    const int b  = blockIdx.x * 4 + wv;
    const float* hr = hlast + b * NHID;
    float s = 0.f;
#pragma unroll
    for (int j = 0; j < 8; ++j) s += hr[l + 64 * j] * wfc[l + 64 * j];
#pragma unroll
    for (int off = 32; off; off >>= 1) s += __shfl_xor(s, off, 64);
    if (l == 0) out[b] = s + bfc[0];
}

extern "C" void kernel_launch(void* const* d_in, const int* in_sizes, int n_in,
                              void* d_out, int out_size, void* d_ws, size_t ws_size,
                              hipStream_t stream) {
    const float* x    = (const float*)d_in[0];
    const float* wih0 = (const float*)d_in[1];
    const float* whh0 = (const float*)d_in[2];
    const float* bih0 = (const float*)d_in[3];
    const float* bhh0 = (const float*)d_in[4];
    const float* wih1 = (const float*)d_in[5];
    const float* whh1 = (const float*)d_in[6];
    const float* bih1 = (const float*)d_in[7];
    const float* bhh1 = (const float*)d_in[8];
    const float* wfc  = (const float*)d_in[9];
    const float* bfc  = (const float*)d_in[10];
    float* out = (float*)d_out;

    char* ws = (char*)d_ws;
    const size_t XPK_ELEMS  = (size_t)NBATCH * T_STEPS * DIN;
    const size_t FLAG_ELEMS = (size_t)NGRP2 * CBLK * FSTRIDE;   // 16384 dwords
    size_t off = 0;
    f16* xpk = (f16*)(ws + off);        off += XPK_ELEMS * 2;
    f16* hb0 = (f16*)(ws + off);        off += (size_t)2 * NBATCH * NHID * 2;
    f16* hb1 = (f16*)(ws + off);        off += (size_t)2 * NBATCH * NHID * 2;
    float* hlast = (float*)(ws + off);  off += (size_t)NBATCH * NHID * 4;
    unsigned* flg0 = (unsigned*)(ws + off); off += FLAG_ELEMS * 4;
    unsigned* flg1 = (unsigned*)(ws + off); off += FLAG_ELEMS * 4;

    // flag counters must be zero every call (graph replays!)
    hipMemsetAsync(flg0, 0, 2 * FLAG_ELEMS * 4, stream);

    pack_x<<<(int)(XPK_ELEMS / 4 / 256), 256, 0, stream>>>(x, xpk);

    {
        const f16* in0 = xpk;
        void* a[] = { (void*)&in0,
                      (void*)&wih0, (void*)&whh0, (void*)&bih0, (void*)&bhh0,
                      (void*)&wih1, (void*)&whh1, (void*)&bih1, (void*)&bhh1,
                      (void*)&hb0, (void*)&hb1, (void*)&hlast,
                      (void*)&flg0, (void*)&flg1 };
        hipLaunchCooperativeKernel(lstm_fused, dim3(256), dim3(512), a, 0, stream);
    }

    fc_kernel<<<64, 256, 0, stream>>>(hlast, wfc, bfc, out);
}

// Round 18
// 4935.062 us; speedup vs baseline: 1.3801x; 1.2454x over previous
//
#include <hip/hip_runtime.h>

// 2-layer LSTM (B=256,T=512,D=64,H=512) + FC, fp16 MFMA / fp32 accum.
// v18 = v13b EXACT (R14, PROVEN BEST 4.90ms). Two independent batch-group
// chains per block (16 groups x 16 batches). Block (pid,jb) serves groups
// gA=2pid, gB=2pid+1 with SHARED weight registers. Per iteration:
// handoff A -> issue B loads -> GEMM A (hides B-load latency) -> publish A ->
// stage B -> GEMM B -> publish B. Exchange protocol = PROVEN sc1/IF relaxed
// atomics + vmcnt(0) + monotonic hot-line flags + bounded poll.
// R15 (4 chains) and R17 (preloaded handoffs) both REGRESSED; this is the
// empirical optimum of the design space.

typedef _Float16 f16;
typedef _Float16 f16x8 __attribute__((ext_vector_type(8)));
typedef _Float16 f16x4 __attribute__((ext_vector_type(4)));
typedef float    f32x4 __attribute__((ext_vector_type(4)));
typedef unsigned long long u64;

#define T_STEPS 512
#define NBATCH  256
#define DIN     64
#define NHID    512
#define GB      16          // batches per group
#define CBLK    32          // blocks (hid slices) per group
#define NGRP2   16          // number of groups
#define NROWS   64          // gate rows per block: 4 gates x 16 hidden
#define HS      (NHID + 8)  // padded tile row stride (f16)
#define XS      (DIN + 8)
#define FSTRIDE 32          // dwords per flag line (128B)

__device__ __forceinline__ f32x4 mfma16(f16x8 a, f16x8 b, f32x4 c) {
    return __builtin_amdgcn_mfma_f32_16x16x32_f16(a, b, c, 0, 0, 0);
}

__device__ __forceinline__ f16x8 cvt8(const float* p) {
    const float4 v0 = *reinterpret_cast<const float4*>(p);
    const float4 v1 = *reinterpret_cast<const float4*>(p + 4);
    f16x8 r;
    r[0] = (f16)v0.x; r[1] = (f16)v0.y; r[2] = (f16)v0.z; r[3] = (f16)v0.w;
    r[4] = (f16)v1.x; r[5] = (f16)v1.y; r[6] = (f16)v1.z; r[7] = (f16)v1.w;
    return r;
}

__device__ __forceinline__ void act4(const f32x4 gv, const int gate,
                                     float* cc, float* hh)
{
#pragma unroll
    for (int jj = 0; jj < 4; ++jj) {
        const float v  = gv[jj];
        const float xs = (gate == 2) ? 2.0f * v : v;
        const float ee = exp2f(-1.44269504f * xs);
        const float sg = 1.0f / (1.0f + ee);
        const float a  = (gate == 2) ? (2.0f * sg - 1.0f) : sg;   // g uses tanh
        const float a1 = __shfl_xor(a, 1, 64);
        const float a2 = __shfl_xor(a, 2, 64);
        const float a3 = __shfl_xor(a, 3, 64);
        int d;
        float vi, vf, vg, vo;
        d = gate;     vi = d == 0 ? a : d == 1 ? a1 : d == 2 ? a2 : a3;
        d = gate ^ 1; vf = d == 0 ? a : d == 1 ? a1 : d == 2 ? a2 : a3;
        d = gate ^ 2; vg = d == 0 ? a : d == 1 ? a1 : d == 2 ? a2 : a3;
        d = gate ^ 3; vo = d == 0 ? a : d == 1 ? a1 : d == 2 ? a2 : a3;
        const float cn = vf * cc[jj] + vi * vg;
        cc[jj] = cn;
        const float e2 = exp2f(-2.88539008f * cn);   // tanh(c) = 2/(1+e^-2c)-1
        const float th = 2.0f / (1.0f + e2) - 1.0f;
        hh[jj] = vo * th;
    }
}

__global__ __launch_bounds__(512, 2) void lstm_fused(
    const f16*  __restrict__ xpk,      // [T][B][DIN] fp16 time-major
    const float* __restrict__ wih0, const float* __restrict__ whh0,
    const float* __restrict__ bih0, const float* __restrict__ bhh0,
    const float* __restrict__ wih1, const float* __restrict__ whh1,
    const float* __restrict__ bih1, const float* __restrict__ bhh1,
    f16* __restrict__ hbuf0,           // [2][B][NHID] layer0 h exchange
    f16* __restrict__ hbuf1,           // [2][B][NHID] layer1 h exchange
    float* __restrict__ hlast,         // [B][NHID] f32 final h1
    unsigned* flags0, unsigned* flags1) // [NGRP2*CBLK*FSTRIDE] monotonic, memset 0
{
    __shared__ f16 hT0A[GB * HS], hT0B[GB * HS];   // h0 tiles, chains A/B
    __shared__ f16 hT1A[GB * HS], hT1B[GB * HS];   // h1 tiles
    __shared__ f16 xTile[2][3][GB * XS];           // x tiles [chain][slot]
    __shared__ f16 hs0[2][2][GB * 16];             // publish stage [chain][par]
    __shared__ f16 hs1[2][2][GB * 16];
    __shared__ float Lb0[NROWS], Lb1[NROWS];
    __shared__ unsigned pubcnt[2][2][2];           // [eng][chain][par]

    const int tid = threadIdx.x;
    const int pid = blockIdx.x & 7;
    const int jb  = blockIdx.x >> 3;
    const int gA  = pid * 2, gB_ = pid * 2 + 1;
    const int bbA = gA * GB, bbB = gB_ * GB;

    if (tid < 8) reinterpret_cast<unsigned*>(pubcnt)[tid] = 0u;
    if (tid < NROWS) {
        const int gr = (tid & 3) * NHID + jb * 16 + (tid >> 2);
        Lb0[tid] = bih0[gr] + bhh0[gr];
        Lb1[tid] = bih1[gr] + bhh1[gr];
    }

    const int w    = tid >> 6;          // wave 0..7
    const int eng  = w >> 2;            // 0: layer0, 1: layer1
    const int wr   = w & 3;
    const int l    = tid & 63;
    const int col  = l & 15;
    const int q    = l >> 4;
    const int q8   = q << 3;
    const int n    = (wr << 4) | col;   // gate row 0..63
    const int gate = n & 3;
    const int hl   = n >> 2;
    const int grow = (n & 3) * NHID + jb * 16 + (n >> 2);
    const int rb   = (wr << 2) | (l & 3);   // staging row 0..15
    const int rc   = l >> 2;                // staging chunk 0..15

    // ---- weights -> registers (one-time), f32->f16; SHARED by both chains ----
    f16x8 BWx[16], BWh[16];
    if (eng == 0) {
        const float* sx = wih0 + (size_t)grow * DIN + q8;
#pragma unroll
        for (int s = 0; s < 2; ++s) BWx[s] = cvt8(sx + s * 32);
        const float* sh = whh0 + (size_t)grow * NHID + q8;
#pragma unroll
        for (int s = 0; s < 16; ++s) BWh[s] = cvt8(sh + s * 32);
    } else {
        const float* sx = wih1 + (size_t)grow * NHID + q8;
#pragma unroll
        for (int s = 0; s < 16; ++s) BWx[s] = cvt8(sx + s * 32);
        const float* sh = whh1 + (size_t)grow * NHID + q8;
#pragma unroll
        for (int s = 0; s < 16; ++s) BWh[s] = cvt8(sh + s * 32);
    }
    __syncthreads();
    const float bias_n = (eng == 0) ? Lb0[n] : Lb1[n];

    float cA[4] = {0,0,0,0}, cB[4] = {0,0,0,0};   // cell state per chain

    // ---- bounded wave-parallel poll of a group's 32 producer counters ----
    auto pollf = [&](const unsigned* flg, int grp, int sp) {
        const unsigned target = (unsigned)(sp + 1);
        const unsigned* fp = flg + (size_t)(grp * CBLK + (l & 31)) * FSTRIDE;
        unsigned spins = 0;
        for (;;) {
            unsigned v = 0xFFFFFFFFu;
            if (l < CBLK)
                v = __hip_atomic_load(fp, __ATOMIC_RELAXED, __HIP_MEMORY_SCOPE_AGENT);
            if (__all(v >= target)) break;
            __builtin_amdgcn_s_sleep(2);
            if (++spins > (1u << 15)) break;   // fail finite, never hang
        }
        asm volatile("" ::: "memory");
    };

    // issue 8x8B sc1 loads of one 16x512 h tile slice (use deferred by compiler)
    auto ldissue = [&](u64* r, const f16* hb, int par, int bb) {
        const u64* src = reinterpret_cast<const u64*>(
            hb + (size_t)par * (NBATCH * NHID) + (size_t)(bb + rb) * NHID) + rc * 8;
#pragma unroll
        for (int j = 0; j < 8; ++j)
            r[j] = __hip_atomic_load(src + j, __ATOMIC_RELAXED, __HIP_MEMORY_SCOPE_AGENT);
    };
    auto tilewr = [&](f16* t, const u64* r) {
        f16* dst = t + rb * HS + rc * 32;
#pragma unroll
        for (int j = 0; j < 8; ++j)
            *reinterpret_cast<u64*>(dst + j * 4) = r[j];
    };

    // in-compute per-wave stripe publish (R12): sc1 stores -> own vmcnt(0) ->
    // LDS counter; 4th wave writes flag = sp+1.
    auto pubwave = [&](f16* hb, unsigned* flg, int grp, int bb, const f16* hsrc,
                       int sp, int eci, int cci) {
        asm volatile("s_waitcnt lgkmcnt(0)" ::: "memory");
        if (l < GB) {
            const u64 v8 = *reinterpret_cast<const u64*>(hsrc + l * 16 + wr * 4);
            u64* dst = reinterpret_cast<u64*>(
                hb + (size_t)(sp & 1) * (NBATCH * NHID)
                   + (size_t)(bb + l) * NHID + jb * 16 + wr * 4);
            __hip_atomic_store(dst, v8, __ATOMIC_RELAXED, __HIP_MEMORY_SCOPE_AGENT);
        }
        asm volatile("s_waitcnt vmcnt(0)" ::: "memory");
        if (l == 0) {
            const unsigned old = atomicAdd(&pubcnt[eci][cci][sp & 1], 1u);
            if (old == 3u) {
                pubcnt[eci][cci][sp & 1] = 0u;
                __hip_atomic_store(flg + (size_t)(grp * CBLK + jb) * FSTRIDE,
                                   (unsigned)(sp + 1),
                                   __ATOMIC_RELAXED, __HIP_MEMORY_SCOPE_AGENT);
            }
        }
    };

    // ---- eng0 step for one chain: K=64 x-GEMM + K=512 h-GEMM, act, publish ----
    auto comp0 = [&](const f16* xp, const f16* t0, float* cc, f16* hst,
                     int grp, int bb, int s_, bool doh, int cci) {
        f32x4 e0 = {bias_n, bias_n, bias_n, bias_n};
        f32x4 o0 = {0,0,0,0};
#pragma unroll
        for (int k = 0; k < 2; ++k) {
            const f16x8 a0 = *reinterpret_cast<const f16x8*>(xp + col * XS + (q + 4*k) * 8);
            if (k & 1) o0 = mfma16(a0, BWx[k], o0); else e0 = mfma16(a0, BWx[k], e0);
        }
        if (doh) {
#pragma unroll
            for (int k = 0; k < 16; ++k) {
                const f16x8 a0 = *reinterpret_cast<const f16x8*>(t0 + col * HS + (q + 4*k) * 8);
                if (k & 1) o0 = mfma16(a0, BWh[k], o0); else e0 = mfma16(a0, BWh[k], e0);
            }
        }
        const f32x4 gv = e0 + o0;
        float hv[4];
        act4(gv, gate, cc, hv);
        if (gate == 0) {
#pragma unroll
            for (int jj = 0; jj < 4; ++jj)
                hst[(q * 4 + jj) * 16 + hl] = (f16)hv[jj];
        }
        pubwave(hbuf0, flags0, grp, bb, hst, s_, 0, cci);
    };

    // ---- eng1 step for one chain: K=512 x-GEMM (h0) + K=512 h-GEMM (h1) ----
    auto comp1 = [&](const f16* t0, const f16* t1, float* cc, f16* hst,
                     int grp, int bb, int sp_, bool doh2, bool last, int cci) {
        f32x4 e0 = {bias_n, bias_n, bias_n, bias_n};
        f32x4 o0 = {0,0,0,0};
#pragma unroll
        for (int k = 0; k < 16; ++k) {
            const f16x8 a0 = *reinterpret_cast<const f16x8*>(t0 + col * HS + (q + 4*k) * 8);
            if (k & 1) o0 = mfma16(a0, BWx[k], o0); else e0 = mfma16(a0, BWx[k], e0);
        }
        if (doh2) {
#pragma unroll
            for (int k = 0; k < 16; ++k) {
                const f16x8 a0 = *reinterpret_cast<const f16x8*>(t1 + col * HS + (q + 4*k) * 8);
                if (k & 1) o0 = mfma16(a0, BWh[k], o0); else e0 = mfma16(a0, BWh[k], e0);
            }
        }
        const f32x4 gv = e0 + o0;
        float hv[4];
        act4(gv, gate, cc, hv);
        if (last) {
            if (gate == 0) {
#pragma unroll
                for (int jj = 0; jj < 4; ++jj)
                    hlast[(size_t)(bb + q * 4 + jj) * NHID + jb * 16 + hl] = hv[jj];
            }
        } else {
            if (gate == 0) {
#pragma unroll
                for (int jj = 0; jj < 4; ++jj)
                    hst[(q * 4 + jj) * 16 + hl] = (f16)hv[jj];
            }
            pubwave(hbuf1, flags1, grp, bb, hst, sp_, 1, cci);
        }
    };

    // ---- prologue: stage xT slots 0,1 for both chains ----
    if (eng == 0) {
#pragma unroll
        for (int t0 = 0; t0 < 2; ++t0) {
            const u64 vA = *reinterpret_cast<const u64*>(
                xpk + ((size_t)t0 * NBATCH + bbA + rb) * DIN + rc * 4);
            const u64 vB = *reinterpret_cast<const u64*>(
                xpk + ((size_t)t0 * NBATCH + bbB + rb) * DIN + rc * 4);
            *reinterpret_cast<u64*>(xTile[0][t0] + rb * XS + rc * 4) = vA;
            *reinterpret_cast<u64*>(xTile[1][t0] + rb * XS + rc * 4) = vB;
        }
    }
    __syncthreads();

    u64 rA[8], rB[8];
    for (int s = 0; s <= T_STEPS; ++s) {
        const bool doh0 = (s >= 1);
        const bool doh1 = (s >= 2);
        // ---- handoff chain A ----
        if (eng == 0) {
            if (doh0) { pollf(flags0, gA, s - 1); ldissue(rA, hbuf0, (s - 1) & 1, bbA); tilewr(hT0A, rA); }
        } else {
            if (doh1) { pollf(flags1, gA, s - 2); ldissue(rA, hbuf1, (s - 2) & 1, bbA); tilewr(hT1A, rA); }
        }
        __syncthreads();   // B1a: A tiles staged
        // ---- issue chain B loads (latency hides under GEMM A) ----
        if (eng == 0) {
            if (doh0) { pollf(flags0, gB_, s - 1); ldissue(rB, hbuf0, (s - 1) & 1, bbB); }
        } else {
            if (doh1) { pollf(flags1, gB_, s - 2); ldissue(rB, hbuf1, (s - 2) & 1, bbB); }
        }
        // ---- compute chain A ----
        if (eng == 0) {
            if (s < T_STEPS)
                comp0(xTile[0][s % 3], hT0A, cA, hs0[0][s & 1], gA, bbA, s, doh0, 0);
        } else {
            if (s >= 1)
                comp1(hT0A, hT1A, cA, hs1[0][(s - 1) & 1], gA, bbA, s - 1, doh1,
                      s == T_STEPS, 0);
        }
        // ---- stage chain B tiles ----
        if (eng == 0) { if (doh0) tilewr(hT0B, rB); }
        else          { if (doh1) tilewr(hT1B, rB); }
        __syncthreads();   // B1b: B tiles staged
        // ---- compute chain B (+ xT staging for s+2) ----
        if (eng == 0) {
            if (s < T_STEPS)
                comp0(xTile[1][s % 3], hT0B, cB, hs0[1][s & 1], gB_, bbB, s, doh0, 1);
            if (s + 2 < T_STEPS) {
                const u64 vA = *reinterpret_cast<const u64*>(
                    xpk + ((size_t)(s + 2) * NBATCH + bbA + rb) * DIN + rc * 4);
                const u64 vB = *reinterpret_cast<const u64*>(
                    xpk + ((size_t)(s + 2) * NBATCH + bbB + rb) * DIN + rc * 4);
                *reinterpret_cast<u64*>(xTile[0][(s + 2) % 3] + rb * XS + rc * 4) = vA;
                *reinterpret_cast<u64*>(xTile[1][(s + 2) % 3] + rb * XS + rc * 4) = vB;
            }
        } else {
            if (s >= 1)
                comp1(hT0B, hT1B, cB, hs1[1][(s - 1) & 1], gB_, bbB, s - 1, doh1,
                      s == T_STEPS, 1);
        }
        __syncthreads();   // B2
    }
}

// x [B][T][DIN] f32 -> xp [T][B][DIN] f16 (write-coalesced transpose)
__global__ void pack_x(const float* __restrict__ xin, f16* __restrict__ xp) {
    const int i = blockIdx.x * 256 + threadIdx.x;
    const long long e = (long long)i * 4;
    const int d = (int)(e & (DIN - 1));
    const int b = (int)((e >> 6) & (NBATCH - 1));
    const int t = (int)(e >> 14);
    if (t < T_STEPS) {
        const float4 v = *reinterpret_cast<const float4*>(
            xin + ((size_t)b * T_STEPS + t) * DIN + d);
        f16x4 o;
        o[0] = (f16)v.x; o[1] = (f16)v.y; o[2] = (f16)v.z; o[3] = (f16)v.w;
        *reinterpret_cast<f16x4*>(xp + ((size_t)t * NBATCH + b) * DIN + d) = o;
    }
}

__global__ void fc_kernel(const float* __restrict__ hlast, const float* __restrict__ wfc,
                          const float* __restrict__ bfc, float* __restrict__ out) {
    const int wv = threadIdx.x >> 6, l = threadIdx.x & 63;
    const int b  = blockIdx.x * 4 + wv;
    const float* hr = hlast + b * NHID;
    float s = 0.f;
#pragma unroll
    for (int j = 0; j < 8; ++j) s += hr[l + 64 * j] * wfc[l + 64 * j];
#pragma unroll
    for (int off = 32; off; off >>= 1) s += __shfl_xor(s, off, 64);
    if (l == 0) out[b] = s + bfc[0];
}

extern "C" void kernel_launch(void* const* d_in, const int* in_sizes, int n_in,
                              void* d_out, int out_size, void* d_ws, size_t ws_size,
                              hipStream_t stream) {
    const float* x    = (const float*)d_in[0];
    const float* wih0 = (const float*)d_in[1];
    const float* whh0 = (const float*)d_in[2];
    const float* bih0 = (const float*)d_in[3];
    const float* bhh0 = (const float*)d_in[4];
    const float* wih1 = (const float*)d_in[5];
    const float* whh1 = (const float*)d_in[6];
    const float* bih1 = (const float*)d_in[7];
    const float* bhh1 = (const float*)d_in[8];
    const float* wfc  = (const float*)d_in[9];
    const float* bfc  = (const float*)d_in[10];
    float* out = (float*)d_out;

    char* ws = (char*)d_ws;
    const size_t XPK_ELEMS  = (size_t)NBATCH * T_STEPS * DIN;
    const size_t FLAG_ELEMS = (size_t)NGRP2 * CBLK * FSTRIDE;   // 16384 dwords
    size_t off = 0;
    f16* xpk = (f16*)(ws + off);        off += XPK_ELEMS * 2;
    f16* hb0 = (f16*)(ws + off);        off += (size_t)2 * NBATCH * NHID * 2;
    f16* hb1 = (f16*)(ws + off);        off += (size_t)2 * NBATCH * NHID * 2;
    float* hlast = (float*)(ws + off);  off += (size_t)NBATCH * NHID * 4;
    unsigned* flg0 = (unsigned*)(ws + off); off += FLAG_ELEMS * 4;
    unsigned* flg1 = (unsigned*)(ws + off); off += FLAG_ELEMS * 4;

    // flag counters must be zero every call (graph replays!)
    hipMemsetAsync(flg0, 0, 2 * FLAG_ELEMS * 4, stream);

    pack_x<<<(int)(XPK_ELEMS / 4 / 256), 256, 0, stream>>>(x, xpk);

    {
        const f16* in0 = xpk;
        void* a[] = { (void*)&in0,
                      (void*)&wih0, (void*)&whh0, (void*)&bih0, (void*)&bhh0,
                      (void*)&wih1, (void*)&whh1, (void*)&bih1, (void*)&bhh1,
                      (void*)&hb0, (void*)&hb1, (void*)&hlast,
                      (void*)&flg0, (void*)&flg1 };
        hipLaunchCooperativeKernel(lstm_fused, dim3(256), dim3(512), a, 0, stream);
    }

    fc_kernel<<<64, 256, 0, stream>>>(hlast, wfc, bfc, out);
}